// Round 1
// 180.355 us; speedup vs baseline: 1.0071x; 1.0071x over previous
//
#include <hip/hip_runtime.h>
#include <hip/hip_bf16.h>
#include <stdint.h>

// ---------------------------------------------------------------------------
// Net_71373766525077: SNN leaky layer.
//   cur = x @ W^T   (1024x4096 @ 4096x4096 fp32; mem tol 7.92 -> bf16 MFMA)
//   scan t: reset=(mem>1); mem=0.9*mem+cur[t]-reset; spk=(mem>1)
//   out = concat(spk_rec[T][N], mem_rec[T][N]) fp32
//
// R12 -> R13: replace the m97-style 128x128 2-barrier GEMM (614 TF, MfmaUtil
// 23.6%, 1.26e7 LDS bank conflicts) with the verified 256x256 8-phase
// schedule (T2 swizzle + T3/T4 counted-vmcnt + T5 setprio; m201 = 1563 TF
// @4k). Split-K S=4 -> 256 blocks = 1/CU (128KB LDS). Swizzle is
// linear-LDS-dest + inverse-swizzled global source (rule 21), col ^=
// (row&7)<<3 on ds_read. vmcnt(4) only at phases 3/7; never 0 in steady
// state. Scan gains NPART=4. Predicted gemm 56 -> ~28us, total ~155us.
// ---------------------------------------------------------------------------

typedef __attribute__((ext_vector_type(8))) short bf16x8;
typedef __attribute__((ext_vector_type(4))) float floatx4;

#define T_STEPS 1024
#define N_IN    4096
#define N_OUT   4096

#define PH_T 128                  // timesteps per scan phase
#define NPH  (T_STEPS / PH_T)     // 8 phases
#define NB_N 16                   // neurons per scan block
#define TP   130                  // LDS t-stride (floats)

#define TN ((size_t)T_STEPS * N_OUT)

__device__ __forceinline__ unsigned short f2bf_rne(float f) {
    unsigned int u = __builtin_bit_cast(unsigned int, f);
    unsigned int r = 0x7FFFu + ((u >> 16) & 1u);
    return (unsigned short)((u + r) >> 16);
}

__device__ __forceinline__ float bf2f(unsigned short b) {
    unsigned int u = ((unsigned int)b) << 16;
    return __builtin_bit_cast(float, u);
}

// One kernel converts both inputs (x then W), float4/ushort4 vectorized.
__global__ __launch_bounds__(256) void cvt2_kernel(const float4* __restrict__ inX,
                                                   ushort4* __restrict__ outX, int n4x,
                                                   const float4* __restrict__ inW,
                                                   ushort4* __restrict__ outW, int n4w) {
    int i = blockIdx.x * blockDim.x + threadIdx.x;
    const float4* in;
    ushort4* out;
    int k;
    if (i < n4x) { in = inX; out = outX; k = i; }
    else         { in = inW; out = outW; k = i - n4x; if (k >= n4w) return; }
    float4 v = in[k];
    ushort4 o;
    o.x = f2bf_rne(v.x);
    o.y = f2bf_rne(v.y);
    o.z = f2bf_rne(v.z);
    o.w = f2bf_rne(v.w);
    out[k] = o;
}

__device__ __forceinline__ void gload16(const void* g, void* l) {
    __builtin_amdgcn_global_load_lds((const __attribute__((address_space(1))) void*)g,
                                     (__attribute__((address_space(3))) void*)l,
                                     16, 0, 0);
}

#define SB0()  __builtin_amdgcn_sched_barrier(0)
#define BARR() __builtin_amdgcn_s_barrier()

// ---------------------------------------------------------------------------
// 8-phase 256x256 GEMM, Pb[z][T][N] = A[M][kz] * B[N][kz]^T, bf16 in/out.
// grid = 64*S blocks x 512 thr; z = bid>>6, m_tile = (bid>>4)&3, n_tile=bid&15.
// 8 waves 2Mx4N, per-wave C = 128x64 (acc[8][4] of 16x16 frags).
// LDS 128KB: A@[b*16384], B@[32768+b*16384], each 256 rows x 64 bf16.
// Swizzled element layout: LDS(row, col ^ ((row&7)<<3)); staged via linear
// global_load_lds with source col pre-permuted ((lane&7)^(lane>>3))<<3.
// Phase schedule per iteration i (tiles t0=2i from buf0, t1=2i+1 from buf1):
//   p0: rd A0q0+B0q0, st buf1.Ah0(t1)   p4: rd A1q0+B1q0, st buf0.Ah0(t2)
//   p1: rd B0q1,      st buf1.Ah1(t1)   p5: rd B1q1,      st buf0.Ah1(t2)
//   p2: rd A0q1,      st buf0.Bh0(t2)   p6: rd A1q1,      st buf1.Bh0(t3)
//   p3: -,            st buf0.Bh1(t2)   p7: -,            st buf1.Bh1(t3)
//   vmcnt(4) at end of p3 (retires buf1 A) and p7 (retires buf0 A+B).
// Every stage provably lands after the last ds_read of the half it overwrites
// (reads drained by per-phase lgkmcnt(0) + the following barrier).
// ---------------------------------------------------------------------------
__global__ __launch_bounds__(512, 2) void gemm8(const short* __restrict__ A,
                                                const short* __restrict__ B,
                                                unsigned short* __restrict__ Pb,
                                                int kLen) {
    __shared__ short lds[65536];  // 128 KB

    const int tid  = threadIdx.x;
    const int lane = tid & 63;
    const int wv   = tid >> 6;          // 0..7
    const int wm   = (wv >> 2) * 128;   // M-wave offset: 0 / 128
    const int wn   = (wv & 3) * 64;     // N-wave offset: 0/64/128/192

    const int bid  = blockIdx.x;
    const int z    = bid >> 6;
    const int tile = bid & 63;
    const long bm  = (long)(tile >> 4) * 256;
    const long bn  = (long)(tile & 15) * 256;
    const int kBeg = z * kLen;
    unsigned short* __restrict__ Pz = Pb + (size_t)z * TN;
    const int NT    = kLen / 64;   // K-tiles of 64
    const int NITER = NT / 2;      // 2 K-tiles per iteration

    // staging source geometry: lane covers row (lane>>3), 16B slot (lane&7);
    // source col block pre-permuted so linear LDS ends up XOR-swizzled.
    const int srow = lane >> 3;                     // 0..7
    const int scol = ((lane & 7) ^ srow) << 3;      // inverse-swizzled col
    const short* aSrc = A + (bm + wv * 8 + srow) * (long)N_IN + kBeg + scol;
    const short* bSrc = B + (bn + wv * 8 + srow) * (long)N_IN + kBeg + scol;
    const int ldA = wv * 512;            // + b*16384 + h*8192 + q*4096 (shorts)
    const int ldB = 32768 + wv * 512;

    // fragment read geometry (16x16x32 MFMA), swizzle applied on read
    const int fm    = lane & 15;
    const int fko   = (lane >> 4) * 8;
    const int cbase = fko ^ ((fm & 7) << 3);

    floatx4 acc[8][4] = {};
    bf16x8 af[4][2];      // A frags of current qm: [mi][ks]
    bf16x8 bq[2][2][2];   // B frags both qn: [qn][nj][ks]

    auto loadA = [&](int b, int qm) {
#pragma unroll
        for (int mi = 0; mi < 4; ++mi)
#pragma unroll
            for (int ks = 0; ks < 2; ++ks)
                af[mi][ks] = *(const bf16x8*)(
                    lds + b * 16384 + (wm + qm * 64 + mi * 16 + fm) * 64 +
                    (cbase ^ (ks << 5)));
    };
    auto loadB = [&](int b, int qn) {
#pragma unroll
        for (int nj = 0; nj < 2; ++nj)
#pragma unroll
            for (int ks = 0; ks < 2; ++ks)
                bq[qn][nj][ks] = *(const bf16x8*)(
                    lds + 32768 + b * 16384 + (wn + qn * 32 + nj * 16 + fm) * 64 +
                    (cbase ^ (ks << 5)));
    };
    auto mfma16 = [&](int qm, int qn) {
        __builtin_amdgcn_s_setprio(1);
#pragma unroll
        for (int ks = 0; ks < 2; ++ks)
#pragma unroll
            for (int mi = 0; mi < 4; ++mi)
#pragma unroll
                for (int nj = 0; nj < 2; ++nj)
                    acc[qm * 4 + mi][qn * 2 + nj] =
                        __builtin_amdgcn_mfma_f32_16x16x32_bf16(
                            af[mi][ks], bq[qn][nj][ks],
                            acc[qm * 4 + mi][qn * 2 + nj], 0, 0, 0);
        __builtin_amdgcn_s_setprio(0);
    };
    // one half-operand = 128 rows x 64 bf16 = 2 gload rounds (q=0,1)
    auto stageA = [&](int b, int h, int t) {
        const short* s = aSrc + (size_t)(h * 128) * N_IN + t * 64;
        gload16(s,                    lds + b * 16384 + h * 8192 + ldA);
        gload16(s + (size_t)64 * N_IN, lds + b * 16384 + h * 8192 + 4096 + ldA);
    };
    auto stageB = [&](int b, int h, int t) {
        const short* s = bSrc + (size_t)(h * 128) * N_IN + t * 64;
        gload16(s,                    lds + b * 16384 + h * 8192 + ldB);
        gload16(s + (size_t)64 * N_IN, lds + b * 16384 + h * 8192 + 4096 + ldB);
    };

    // ---- prologue: full tile0 -> buf0, tile1 B-halves -> buf1 (12 loads) ----
    stageA(0, 0, 0); stageA(0, 1, 0);
    stageB(0, 0, 0); stageB(0, 1, 0);
    stageB(1, 0, 1); stageB(1, 1, 1);
    asm volatile("s_waitcnt vmcnt(4)" ::: "memory");  // buf0 landed; buf1.B in flight
    SB0();
    BARR();

    for (int i = 0; i < NITER; ++i) {
        const int t1 = 2 * i + 1;
        const int t2 = 2 * i + 2;
        const int t3 = 2 * i + 3;
        const bool more = (i + 1 < NITER);

        // ---- p0: buf0 quadrant (qm0,qn0) ----
        loadA(0, 0); loadB(0, 0);
        stageA(1, 0, t1);
        asm volatile("s_waitcnt lgkmcnt(8)" ::: "memory");
        SB0(); BARR();
        asm volatile("s_waitcnt lgkmcnt(0)" ::: "memory"); SB0();
        mfma16(0, 0);
        SB0(); BARR();

        // ---- p1: buf0 (qm0,qn1) ----
        loadB(0, 1);
        stageA(1, 1, t1);
        SB0(); BARR();
        asm volatile("s_waitcnt lgkmcnt(0)" ::: "memory"); SB0();
        mfma16(0, 1);
        SB0(); BARR();

        // ---- p2: buf0 (qm1,qn0) ----
        loadA(0, 1);
        if (more) stageB(0, 0, t2);
        SB0(); BARR();
        asm volatile("s_waitcnt lgkmcnt(0)" ::: "memory"); SB0();
        mfma16(1, 0);
        SB0(); BARR();

        // ---- p3: buf0 (qm1,qn1); retire buf1 A stages ----
        if (more) stageB(0, 1, t2);
        SB0(); BARR();
        mfma16(1, 1);
        if (more) { asm volatile("s_waitcnt vmcnt(4)" ::: "memory"); }
        else      { asm volatile("s_waitcnt vmcnt(0)" ::: "memory"); }
        SB0(); BARR();

        // ---- p4: buf1 (qm0,qn0) ----
        loadA(1, 0); loadB(1, 0);
        if (more) stageA(0, 0, t2);
        asm volatile("s_waitcnt lgkmcnt(8)" ::: "memory");
        SB0(); BARR();
        asm volatile("s_waitcnt lgkmcnt(0)" ::: "memory"); SB0();
        mfma16(0, 0);
        SB0(); BARR();

        // ---- p5: buf1 (qm0,qn1) ----
        loadB(1, 1);
        if (more) stageA(0, 1, t2);
        SB0(); BARR();
        asm volatile("s_waitcnt lgkmcnt(0)" ::: "memory"); SB0();
        mfma16(0, 1);
        SB0(); BARR();

        // ---- p6: buf1 (qm1,qn0) ----
        loadA(1, 1);
        if (more) stageB(1, 0, t3);
        SB0(); BARR();
        asm volatile("s_waitcnt lgkmcnt(0)" ::: "memory"); SB0();
        mfma16(1, 0);
        SB0(); BARR();

        // ---- p7: buf1 (qm1,qn1); retire buf0 stages ----
        if (more) stageB(1, 1, t3);
        SB0(); BARR();
        mfma16(1, 1);
        if (more) { asm volatile("s_waitcnt vmcnt(4)" ::: "memory"); }
        SB0(); BARR();
    }

    // C/D layout: col(n)=lane&15, row(m)=(lane>>4)*4+reg [m89/m91]
    const int cn = lane & 15;
    const int cm = (lane >> 4) * 4;
#pragma unroll
    for (int mi = 0; mi < 8; ++mi)
#pragma unroll
        for (int nj = 0; nj < 4; ++nj)
#pragma unroll
            for (int r = 0; r < 4; ++r)
                Pz[(bm + wm + mi * 16 + cm + r) * (long)N_OUT + bn + wn + nj * 16 + cn] =
                    f2bf_rne(acc[mi][nj][r]);
}

// Fused scan: 256 blocks x 512 threads; block owns NB_N=16 neurons for ALL t.
// Waves 0-6 (producers): write out phase ph-1 spk/mem from ringMem, stage
// phase ph+1 of Pb (bf16, summing NPART partials) into ringCur. Wave 7
// (consumer, lanes 0..15): serial recurrence ringCur -> ringMem.
template <int NPART>
__global__ __launch_bounds__(512) void scan_kernel(const unsigned short* __restrict__ Pb,
                                                   float* __restrict__ out) {
    __shared__ float ringCur[2][NB_N * TP];   // 16.6 KB
    __shared__ float ringMem[2][NB_N * TP];   // 16.6 KB

    const int tid  = threadIdx.x;
    const int wv   = tid >> 6;     // 0..7
    const int lane = tid & 63;
    const int n0   = blockIdx.x * NB_N;

    const int pn = lane & 15;   // neuron offset within block
    const int tr = lane >> 4;   // t-row 0..3 within a group of 4

    float mem = 0.0f;           // consumer state (wave 7, lanes 0..15)

    // ---- prefill: phase 0 -> ringCur[0] ----
    if (wv < 7) {
        float v[NPART][5];
        int gi[5];
#pragma unroll
        for (int i = 0; i < 5; ++i) {
            int g = wv + 7 * i;
            gi[i] = g;
            if (g < 32) {
                size_t idx = (size_t)(g * 4 + tr) * N_OUT + n0 + pn;
#pragma unroll
                for (int zz = 0; zz < NPART; ++zz)
                    v[zz][i] = bf2f(Pb[(size_t)zz * TN + idx]);
            }
        }
#pragma unroll
        for (int i = 0; i < 5; ++i)
            if (gi[i] < 32) {
                float s = v[0][i];
#pragma unroll
                for (int zz = 1; zz < NPART; ++zz) s += v[zz][i];
                ringCur[0][pn * TP + gi[i] * 4 + tr] = s;
            }
    }
    __syncthreads();

    for (int ph = 0; ph < NPH; ++ph) {
        if (wv < 7) {
            // (a) write out phase ph-1 results
            if (ph >= 1) {
                const float* mr = ringMem[(ph - 1) & 1];
                const size_t tb = (size_t)(ph - 1) * PH_T;
                float mv[5];
                int gi[5];
#pragma unroll
                for (int i = 0; i < 5; ++i) {
                    int g = wv + 7 * i;
                    gi[i] = g;
                    if (g < 32) mv[i] = mr[pn * TP + g * 4 + tr];
                }
#pragma unroll
                for (int i = 0; i < 5; ++i)
                    if (gi[i] < 32) {
                        size_t idx = (tb + gi[i] * 4 + tr) * N_OUT + n0 + pn;
                        out[idx]      = mv[i] > 1.0f ? 1.0f : 0.0f;
                        out[TN + idx] = mv[i];
                    }
            }
            // (b) stage phase ph+1
            if (ph + 1 < NPH) {
                const size_t tb = (size_t)(ph + 1) * PH_T;
                float v[NPART][5];
                int gi[5];
#pragma unroll
                for (int i = 0; i < 5; ++i) {
                    int g = wv + 7 * i;
                    gi[i] = g;
                    if (g < 32) {
                        size_t idx = (tb + g * 4 + tr) * N_OUT + n0 + pn;
#pragma unroll
                        for (int zz = 0; zz < NPART; ++zz)
                            v[zz][i] = bf2f(Pb[(size_t)zz * TN + idx]);
                    }
                }
#pragma unroll
                for (int i = 0; i < 5; ++i)
                    if (gi[i] < 32) {
                        float s = v[0][i];
#pragma unroll
                        for (int zz = 1; zz < NPART; ++zz) s += v[zz][i];
                        ringCur[(ph + 1) & 1][pn * TP + gi[i] * 4 + tr] = s;
                    }
            }
        } else if (lane < 16) {
            // consumer: 128 serial steps out of ringCur[ph&1]
            const float* base = &ringCur[ph & 1][pn * TP];
            float* mbase = &ringMem[ph & 1][pn * TP];
#pragma unroll
            for (int sub = 0; sub < 4; ++sub) {
                float2 buf[16];
#pragma unroll
                for (int q = 0; q < 16; ++q)
                    buf[q] = *(const float2*)&base[sub * 32 + q * 2];
#pragma unroll
                for (int q = 0; q < 16; ++q) {
                    float rst = mem > 1.0f ? 1.0f : 0.0f;
                    mem = fmaf(0.9f, mem, buf[q].x) - rst;
                    float m0 = mem;
                    rst = mem > 1.0f ? 1.0f : 0.0f;
                    mem = fmaf(0.9f, mem, buf[q].y) - rst;
                    float2 mo; mo.x = m0; mo.y = mem;
                    *(float2*)&mbase[sub * 32 + q * 2] = mo;
                }
            }
        }
        __syncthreads();
    }

    // ---- tail: write out phase NPH-1 ----
    if (wv < 7) {
        const float* mr = ringMem[(NPH - 1) & 1];
        const size_t tb = (size_t)(NPH - 1) * PH_T;
        float mv[5];
        int gi[5];
#pragma unroll
        for (int i = 0; i < 5; ++i) {
            int g = wv + 7 * i;
            gi[i] = g;
            if (g < 32) mv[i] = mr[pn * TP + g * 4 + tr];
        }
#pragma unroll
        for (int i = 0; i < 5; ++i)
            if (gi[i] < 32) {
                size_t idx = (tb + gi[i] * 4 + tr) * N_OUT + n0 + pn;
                out[idx]      = mv[i] > 1.0f ? 1.0f : 0.0f;
                out[TN + idx] = mv[i];
            }
    }
}

extern "C" void kernel_launch(void* const* d_in, const int* in_sizes, int n_in,
                              void* d_out, int out_size, void* d_ws, size_t ws_size,
                              hipStream_t stream) {
    const float* x = (const float*)d_in[0];  // [1024][4096] fp32
    const float* W = (const float*)d_in[1];  // [4096][4096] fp32
    float* out = (float*)d_out;              // [2][1024][4096] fp32

    char* ws = (char*)d_ws;
    const size_t xbBytes = (size_t)T_STEPS * N_IN * 2;    // 8 MB
    const size_t WbBytes = (size_t)N_OUT * N_IN * 2;      // 33.6 MB
    const size_t PBytes  = TN * 2;                        // 8.4 MB per bf16 partial
    short* xb = (short*)ws;
    short* Wb = (short*)(ws + xbBytes);
    unsigned short* Pb = (unsigned short*)(ws + xbBytes + WbBytes);

    // Split-K: S=4 -> 256 blocks = 1/CU for the 128KB-LDS 8-phase gemm.
    int S = 1;
    if (ws_size >= xbBytes + WbBytes + 4 * PBytes)      S = 4;
    else if (ws_size >= xbBytes + WbBytes + 2 * PBytes) S = 2;

    {
        const int n4x = T_STEPS * N_IN / 4;
        const int n4w = N_OUT * N_IN / 4;
        const int nthr = n4x + n4w;
        cvt2_kernel<<<(nthr + 255) / 256, 256, 0, stream>>>(
            (const float4*)x, (ushort4*)xb, n4x,
            (const float4*)W, (ushort4*)Wb, n4w);
    }

    gemm8<<<64 * S, 512, 0, stream>>>(xb, Wb, Pb, N_IN / S);

    if (S == 4)      scan_kernel<4><<<N_OUT / NB_N, 512, 0, stream>>>(Pb, out);
    else if (S == 2) scan_kernel<2><<<N_OUT / NB_N, 512, 0, stream>>>(Pb, out);
    else             scan_kernel<1><<<N_OUT / NB_N, 512, 0, stream>>>(Pb, out);
}

// Round 2
// 169.562 us; speedup vs baseline: 1.0712x; 1.0637x over previous
//
#include <hip/hip_runtime.h>
#include <hip/hip_bf16.h>
#include <stdint.h>

// ---------------------------------------------------------------------------
// Net_71373766525077: SNN leaky layer.
//   cur = x @ W^T   (1024x4096 @ 4096x4096 fp32; mem tol 7.92 -> bf16 MFMA)
//   scan t: reset=(mem>1); mem=0.9*mem+cur[t]-reset; spk=(mem>1)
//   out = concat(spk_rec[T][N], mem_rec[T][N]) fp32
//
// R13 -> R14: Pb layout flipped to [z][N][T] (n-major). Rationale: R13's
// gemm win (56->40us) was eaten by scan NPART 2->4 (producer staging was 20
// scalar 2B loads/lane/phase) and the gemm epilogue was 128 scalar 2B
// stores/thread (acc regs are consecutive t, which row-major scatters).
// n-major makes both vectorized: gemm stores uint2 (4 bf16 along t) = 32
// stores/thread; scan stages uint4 (8 bf16 along t) = 4 loads/lane; scan
// out-writes float4 (lane owns 4 consecutive n). K-loop schedule (8-phase,
// T2 swizzle, counted vmcnt, setprio), S=4 split-K: unchanged from R13
// (bank conflicts 0, MfmaUtil 32%). The ~80us fixed OV = two 40us 268MB
// harness re-poison fills (fillBufferAligned) - not addressable here.
// Predicted: gemm 40->~30, scan ~41->~28, total ~160.
// ---------------------------------------------------------------------------

typedef __attribute__((ext_vector_type(8))) short bf16x8;
typedef __attribute__((ext_vector_type(4))) float floatx4;

#define T_STEPS 1024
#define N_IN    4096
#define N_OUT   4096

#define PH_T 128                  // timesteps per scan phase
#define NPH  (T_STEPS / PH_T)     // 8 phases
#define NB_N 16                   // neurons per scan block
#define TP   132                  // LDS t-stride (floats, 16B-aligned rows)

#define TN ((size_t)T_STEPS * N_OUT)

__device__ __forceinline__ unsigned short f2bf_rne(float f) {
    unsigned int u = __builtin_bit_cast(unsigned int, f);
    unsigned int r = 0x7FFFu + ((u >> 16) & 1u);
    return (unsigned short)((u + r) >> 16);
}

__device__ __forceinline__ float bf2f(unsigned short b) {
    unsigned int u = ((unsigned int)b) << 16;
    return __builtin_bit_cast(float, u);
}

// One kernel converts both inputs (x then W), float4/ushort4 vectorized.
__global__ __launch_bounds__(256) void cvt2_kernel(const float4* __restrict__ inX,
                                                   ushort4* __restrict__ outX, int n4x,
                                                   const float4* __restrict__ inW,
                                                   ushort4* __restrict__ outW, int n4w) {
    int i = blockIdx.x * blockDim.x + threadIdx.x;
    const float4* in;
    ushort4* out;
    int k;
    if (i < n4x) { in = inX; out = outX; k = i; }
    else         { in = inW; out = outW; k = i - n4x; if (k >= n4w) return; }
    float4 v = in[k];
    ushort4 o;
    o.x = f2bf_rne(v.x);
    o.y = f2bf_rne(v.y);
    o.z = f2bf_rne(v.z);
    o.w = f2bf_rne(v.w);
    out[k] = o;
}

__device__ __forceinline__ void gload16(const void* g, void* l) {
    __builtin_amdgcn_global_load_lds((const __attribute__((address_space(1))) void*)g,
                                     (__attribute__((address_space(3))) void*)l,
                                     16, 0, 0);
}

#define SB0()  __builtin_amdgcn_sched_barrier(0)
#define BARR() __builtin_amdgcn_s_barrier()

// ---------------------------------------------------------------------------
// 8-phase 256x256 GEMM, Pb[z][N][T] = (A[M][kz] * B[N][kz]^T)^T, bf16 in/out.
// grid = 64*S blocks x 512 thr; z = bid>>6, m_tile = (bid>>4)&3, n_tile=bid&15.
// 8 waves 2Mx4N, per-wave C = 128x64 (acc[8][4] of 16x16 frags).
// LDS 128KB: A@[b*16384], B@[32768+b*16384], each 256 rows x 64 bf16.
// Swizzled element layout: LDS(row, col ^ ((row&7)<<3)); staged via linear
// global_load_lds with source col pre-permuted ((lane&7)^(lane>>3))<<3.
// Phase schedule per iteration i (tiles t0=2i from buf0, t1=2i+1 from buf1):
//   p0: rd A0q0+B0q0, st buf1.Ah0(t1)   p4: rd A1q0+B1q0, st buf0.Ah0(t2)
//   p1: rd B0q1,      st buf1.Ah1(t1)   p5: rd B1q1,      st buf0.Ah1(t2)
//   p2: rd A0q1,      st buf0.Bh0(t2)   p6: rd A1q1,      st buf1.Bh0(t3)
//   p3: -,            st buf0.Bh1(t2)   p7: -,            st buf1.Bh1(t3)
//   vmcnt(4) at end of p3 (retires buf1 A) and p7 (retires buf0 A+B).
// Epilogue: acc frag regs are 4 consecutive t for one n -> pack 4 bf16 and
// global_store_dwordx2 into n-major Pb (32 stores/thread, was 128 scalar).
// ---------------------------------------------------------------------------
__global__ __launch_bounds__(512, 2) void gemm8(const short* __restrict__ A,
                                                const short* __restrict__ B,
                                                unsigned short* __restrict__ Pb,
                                                int kLen) {
    __shared__ short lds[65536];  // 128 KB

    const int tid  = threadIdx.x;
    const int lane = tid & 63;
    const int wv   = tid >> 6;          // 0..7
    const int wm   = (wv >> 2) * 128;   // M-wave offset: 0 / 128
    const int wn   = (wv & 3) * 64;     // N-wave offset: 0/64/128/192

    const int bid  = blockIdx.x;
    const int z    = bid >> 6;
    const int tile = bid & 63;
    const long bm  = (long)(tile >> 4) * 256;
    const long bn  = (long)(tile & 15) * 256;
    const int kBeg = z * kLen;
    unsigned short* __restrict__ Pz = Pb + (size_t)z * TN;
    const int NT    = kLen / 64;   // K-tiles of 64
    const int NITER = NT / 2;      // 2 K-tiles per iteration

    // staging source geometry: lane covers row (lane>>3), 16B slot (lane&7);
    // source col block pre-permuted so linear LDS ends up XOR-swizzled.
    const int srow = lane >> 3;                     // 0..7
    const int scol = ((lane & 7) ^ srow) << 3;      // inverse-swizzled col
    const short* aSrc = A + (bm + wv * 8 + srow) * (long)N_IN + kBeg + scol;
    const short* bSrc = B + (bn + wv * 8 + srow) * (long)N_IN + kBeg + scol;
    const int ldA = wv * 512;            // + b*16384 + h*8192 + q*4096 (shorts)
    const int ldB = 32768 + wv * 512;

    // fragment read geometry (16x16x32 MFMA), swizzle applied on read
    const int fm    = lane & 15;
    const int fko   = (lane >> 4) * 8;
    const int cbase = fko ^ ((fm & 7) << 3);

    floatx4 acc[8][4] = {};
    bf16x8 af[4][2];      // A frags of current qm: [mi][ks]
    bf16x8 bq[2][2][2];   // B frags both qn: [qn][nj][ks]

    auto loadA = [&](int b, int qm) {
#pragma unroll
        for (int mi = 0; mi < 4; ++mi)
#pragma unroll
            for (int ks = 0; ks < 2; ++ks)
                af[mi][ks] = *(const bf16x8*)(
                    lds + b * 16384 + (wm + qm * 64 + mi * 16 + fm) * 64 +
                    (cbase ^ (ks << 5)));
    };
    auto loadB = [&](int b, int qn) {
#pragma unroll
        for (int nj = 0; nj < 2; ++nj)
#pragma unroll
            for (int ks = 0; ks < 2; ++ks)
                bq[qn][nj][ks] = *(const bf16x8*)(
                    lds + 32768 + b * 16384 + (wn + qn * 32 + nj * 16 + fm) * 64 +
                    (cbase ^ (ks << 5)));
    };
    auto mfma16 = [&](int qm, int qn) {
        __builtin_amdgcn_s_setprio(1);
#pragma unroll
        for (int ks = 0; ks < 2; ++ks)
#pragma unroll
            for (int mi = 0; mi < 4; ++mi)
#pragma unroll
                for (int nj = 0; nj < 2; ++nj)
                    acc[qm * 4 + mi][qn * 2 + nj] =
                        __builtin_amdgcn_mfma_f32_16x16x32_bf16(
                            af[mi][ks], bq[qn][nj][ks],
                            acc[qm * 4 + mi][qn * 2 + nj], 0, 0, 0);
        __builtin_amdgcn_s_setprio(0);
    };
    // one half-operand = 128 rows x 64 bf16 = 2 gload rounds (q=0,1)
    auto stageA = [&](int b, int h, int t) {
        const short* s = aSrc + (size_t)(h * 128) * N_IN + t * 64;
        gload16(s,                    lds + b * 16384 + h * 8192 + ldA);
        gload16(s + (size_t)64 * N_IN, lds + b * 16384 + h * 8192 + 4096 + ldA);
    };
    auto stageB = [&](int b, int h, int t) {
        const short* s = bSrc + (size_t)(h * 128) * N_IN + t * 64;
        gload16(s,                    lds + b * 16384 + h * 8192 + ldB);
        gload16(s + (size_t)64 * N_IN, lds + b * 16384 + h * 8192 + 4096 + ldB);
    };

    // ---- prologue: full tile0 -> buf0, tile1 B-halves -> buf1 (12 loads) ----
    stageA(0, 0, 0); stageA(0, 1, 0);
    stageB(0, 0, 0); stageB(0, 1, 0);
    stageB(1, 0, 1); stageB(1, 1, 1);
    asm volatile("s_waitcnt vmcnt(4)" ::: "memory");  // buf0 landed; buf1.B in flight
    SB0();
    BARR();

    for (int i = 0; i < NITER; ++i) {
        const int t1 = 2 * i + 1;
        const int t2 = 2 * i + 2;
        const int t3 = 2 * i + 3;
        const bool more = (i + 1 < NITER);

        // ---- p0: buf0 quadrant (qm0,qn0) ----
        loadA(0, 0); loadB(0, 0);
        stageA(1, 0, t1);
        asm volatile("s_waitcnt lgkmcnt(8)" ::: "memory");
        SB0(); BARR();
        asm volatile("s_waitcnt lgkmcnt(0)" ::: "memory"); SB0();
        mfma16(0, 0);
        SB0(); BARR();

        // ---- p1: buf0 (qm0,qn1) ----
        loadB(0, 1);
        stageA(1, 1, t1);
        SB0(); BARR();
        asm volatile("s_waitcnt lgkmcnt(0)" ::: "memory"); SB0();
        mfma16(0, 1);
        SB0(); BARR();

        // ---- p2: buf0 (qm1,qn0) ----
        loadA(0, 1);
        if (more) stageB(0, 0, t2);
        SB0(); BARR();
        asm volatile("s_waitcnt lgkmcnt(0)" ::: "memory"); SB0();
        mfma16(1, 0);
        SB0(); BARR();

        // ---- p3: buf0 (qm1,qn1); retire buf1 A stages ----
        if (more) stageB(0, 1, t2);
        SB0(); BARR();
        mfma16(1, 1);
        if (more) { asm volatile("s_waitcnt vmcnt(4)" ::: "memory"); }
        else      { asm volatile("s_waitcnt vmcnt(0)" ::: "memory"); }
        SB0(); BARR();

        // ---- p4: buf1 (qm0,qn0) ----
        loadA(1, 0); loadB(1, 0);
        if (more) stageA(0, 0, t2);
        asm volatile("s_waitcnt lgkmcnt(8)" ::: "memory");
        SB0(); BARR();
        asm volatile("s_waitcnt lgkmcnt(0)" ::: "memory"); SB0();
        mfma16(0, 0);
        SB0(); BARR();

        // ---- p5: buf1 (qm0,qn1) ----
        loadB(1, 1);
        if (more) stageA(0, 1, t2);
        SB0(); BARR();
        asm volatile("s_waitcnt lgkmcnt(0)" ::: "memory"); SB0();
        mfma16(0, 1);
        SB0(); BARR();

        // ---- p6: buf1 (qm1,qn0) ----
        loadA(1, 1);
        if (more) stageB(1, 0, t3);
        SB0(); BARR();
        asm volatile("s_waitcnt lgkmcnt(0)" ::: "memory"); SB0();
        mfma16(1, 0);
        SB0(); BARR();

        // ---- p7: buf1 (qm1,qn1); retire buf0 stages ----
        if (more) stageB(1, 1, t3);
        SB0(); BARR();
        mfma16(1, 1);
        if (more) { asm volatile("s_waitcnt vmcnt(4)" ::: "memory"); }
        SB0(); BARR();
    }

    // C/D layout: col(n)=lane&15, row(m=t)=(lane>>4)*4+reg [m89/m91].
    // n-major Pb: 4 regs = 4 consecutive t -> one dwordx2 store per frag.
    const int cn = lane & 15;
    const int cm = (lane >> 4) * 4;
#pragma unroll
    for (int mi = 0; mi < 8; ++mi)
#pragma unroll
        for (int nj = 0; nj < 4; ++nj) {
            unsigned int lo = (unsigned int)f2bf_rne(acc[mi][nj][0]) |
                              ((unsigned int)f2bf_rne(acc[mi][nj][1]) << 16);
            unsigned int hi = (unsigned int)f2bf_rne(acc[mi][nj][2]) |
                              ((unsigned int)f2bf_rne(acc[mi][nj][3]) << 16);
            uint2 v; v.x = lo; v.y = hi;
            size_t nIdx = (size_t)(bn + wn + nj * 16 + cn);
            *(uint2*)(Pz + nIdx * T_STEPS + (size_t)(bm + wm + mi * 16 + cm)) = v;
        }
}

// Fused scan over n-major Pb[z][N][T]: 256 blocks x 512 threads; block owns
// NB_N=16 neurons for ALL t. Waves 0-6 (producers): write out phase ph-1
// spk/mem from ringMem (lane owns 4 consecutive n -> float4 stores). Waves
// 0-3 additionally stage phase ph+1: lane owns (n, 8-t chunk) -> uint4 load
// per partial (16B, 256B-contiguous per 16 lanes), f32-sum, 2x float4 ring
// writes. Wave 7 (consumer, lanes 0..15): serial recurrence ringCur->ringMem.
template <int NPART>
__global__ __launch_bounds__(512) void scan_kernel(const unsigned short* __restrict__ Pb,
                                                   float* __restrict__ out) {
    __shared__ float ringCur[2][NB_N * TP];   // 16.9 KB
    __shared__ float ringMem[2][NB_N * TP];   // 16.9 KB

    const int tid  = threadIdx.x;
    const int wv   = tid >> 6;     // 0..7
    const int lane = tid & 63;
    const int n0   = blockIdx.x * NB_N;

    const int pn = lane & 15;   // consumer: neuron offset within block

    // staging geometry (waves 0-3): li = tid 0..255
    const int sn = tid >> 4;    // neuron 0..15
    const int sc = tid & 15;    // 8-t chunk 0..15

    float mem = 0.0f;           // consumer state (wave 7, lanes 0..15)

    auto stage = [&](int buf, size_t tb) {
        float s[8];
#pragma unroll
        for (int j = 0; j < 8; ++j) s[j] = 0.0f;
#pragma unroll
        for (int zz = 0; zz < NPART; ++zz) {
            const uint4 v = *(const uint4*)(Pb + (size_t)zz * TN +
                                            (size_t)(n0 + sn) * T_STEPS + tb + sc * 8);
            unsigned int w0 = v.x, w1 = v.y, w2 = v.z, w3 = v.w;
            s[0] += __builtin_bit_cast(float, w0 << 16);
            s[1] += __builtin_bit_cast(float, w0 & 0xFFFF0000u);
            s[2] += __builtin_bit_cast(float, w1 << 16);
            s[3] += __builtin_bit_cast(float, w1 & 0xFFFF0000u);
            s[4] += __builtin_bit_cast(float, w2 << 16);
            s[5] += __builtin_bit_cast(float, w2 & 0xFFFF0000u);
            s[6] += __builtin_bit_cast(float, w3 << 16);
            s[7] += __builtin_bit_cast(float, w3 & 0xFFFF0000u);
        }
        float4 f0; f0.x = s[0]; f0.y = s[1]; f0.z = s[2]; f0.w = s[3];
        float4 f1; f1.x = s[4]; f1.y = s[5]; f1.z = s[6]; f1.w = s[7];
        float* rc = &ringCur[buf][sn * TP + sc * 8];
        *(float4*)rc = f0;
        *(float4*)(rc + 4) = f1;
    };

    auto writeOut = [&](int buf, size_t tb) {
        const float* mr = ringMem[buf];
        for (int it = tid; it < 512; it += 448) {
            int t  = it >> 2;
            int nq = it & 3;
            float m0 = mr[(nq * 4 + 0) * TP + t];
            float m1 = mr[(nq * 4 + 1) * TP + t];
            float m2 = mr[(nq * 4 + 2) * TP + t];
            float m3 = mr[(nq * 4 + 3) * TP + t];
            float4 mv; mv.x = m0; mv.y = m1; mv.z = m2; mv.w = m3;
            float4 sv;
            sv.x = m0 > 1.0f ? 1.0f : 0.0f;
            sv.y = m1 > 1.0f ? 1.0f : 0.0f;
            sv.z = m2 > 1.0f ? 1.0f : 0.0f;
            sv.w = m3 > 1.0f ? 1.0f : 0.0f;
            size_t idx = (tb + t) * N_OUT + n0 + nq * 4;
            *(float4*)&out[idx]      = sv;
            *(float4*)&out[TN + idx] = mv;
        }
    };

    // ---- prefill: phase 0 -> ringCur[0] ----
    if (tid < 256) stage(0, 0);
    __syncthreads();

    for (int ph = 0; ph < NPH; ++ph) {
        if (wv < 7) {
            if (ph >= 1) writeOut((ph - 1) & 1, (size_t)(ph - 1) * PH_T);
            if (tid < 256 && ph + 1 < NPH)
                stage((ph + 1) & 1, (size_t)(ph + 1) * PH_T);
        } else if (lane < 16) {
            // consumer: 128 serial steps out of ringCur[ph&1]
            const float* base = &ringCur[ph & 1][pn * TP];
            float* mbase = &ringMem[ph & 1][pn * TP];
#pragma unroll
            for (int sub = 0; sub < 4; ++sub) {
                float2 buf[16];
#pragma unroll
                for (int q = 0; q < 16; ++q)
                    buf[q] = *(const float2*)&base[sub * 32 + q * 2];
#pragma unroll
                for (int q = 0; q < 16; ++q) {
                    float rst = mem > 1.0f ? 1.0f : 0.0f;
                    mem = fmaf(0.9f, mem, buf[q].x) - rst;
                    float m0 = mem;
                    rst = mem > 1.0f ? 1.0f : 0.0f;
                    mem = fmaf(0.9f, mem, buf[q].y) - rst;
                    float2 mo; mo.x = m0; mo.y = mem;
                    *(float2*)&mbase[sub * 32 + q * 2] = mo;
                }
            }
        }
        __syncthreads();
    }

    // ---- tail: write out phase NPH-1 ----
    if (wv < 7) writeOut((NPH - 1) & 1, (size_t)(NPH - 1) * PH_T);
}

extern "C" void kernel_launch(void* const* d_in, const int* in_sizes, int n_in,
                              void* d_out, int out_size, void* d_ws, size_t ws_size,
                              hipStream_t stream) {
    const float* x = (const float*)d_in[0];  // [1024][4096] fp32
    const float* W = (const float*)d_in[1];  // [4096][4096] fp32
    float* out = (float*)d_out;              // [2][1024][4096] fp32

    char* ws = (char*)d_ws;
    const size_t xbBytes = (size_t)T_STEPS * N_IN * 2;    // 8 MB
    const size_t WbBytes = (size_t)N_OUT * N_IN * 2;      // 33.6 MB
    const size_t PBytes  = TN * 2;                        // 8.4 MB per bf16 partial
    short* xb = (short*)ws;
    short* Wb = (short*)(ws + xbBytes);
    unsigned short* Pb = (unsigned short*)(ws + xbBytes + WbBytes);

    // Split-K: S=4 -> 256 blocks = 1/CU for the 128KB-LDS 8-phase gemm.
    int S = 1;
    if (ws_size >= xbBytes + WbBytes + 4 * PBytes)      S = 4;
    else if (ws_size >= xbBytes + WbBytes + 2 * PBytes) S = 2;

    {
        const int n4x = T_STEPS * N_IN / 4;
        const int n4w = N_OUT * N_IN / 4;
        const int nthr = n4x + n4w;
        cvt2_kernel<<<(nthr + 255) / 256, 256, 0, stream>>>(
            (const float4*)x, (ushort4*)xb, n4x,
            (const float4*)W, (ushort4*)Wb, n4w);
    }

    gemm8<<<64 * S, 512, 0, stream>>>(xb, Wb, Pb, N_IN / S);

    if (S == 4)      scan_kernel<4><<<N_OUT / NB_N, 512, 0, stream>>>(Pb, out);
    else if (S == 2) scan_kernel<2><<<N_OUT / NB_N, 512, 0, stream>>>(Pb, out);
    else             scan_kernel<1><<<N_OUT / NB_N, 512, 0, stream>>>(Pb, out);
}